// Round 4
// baseline (433.825 us; speedup 1.0000x reference)
//
#include <hip/hip_runtime.h>
#include <math.h>
#include <stdint.h>

#define HH 4096
#define WW 4096
#define MAXP 8192
#define ALPHA_F 0.9998f
#define ROWCAP 64   // max peaks recorded per row (Poisson(0.82) => P(>64) ~ 1e-80)

// output layout (floats): probs_valid[0..40959], topk_scores[40960..40975],
// cue_dir[40976..40979], sel_peaks[40980..41011]

// ---------------- helpers ----------------
__device__ __forceinline__ float clampA(float v) {
    float t = fminf(fmaxf(v, 0.f), 1.f);
    return (t < ALPHA_F) ? 0.f : t;
}

__device__ __forceinline__ unsigned long long shflx_u64(unsigned long long v, int m) {
    int lo = __shfl_xor((int)(v & 0xFFFFFFFFull), m);
    int hi = __shfl_xor((int)(v >> 32), m);
    return ((unsigned long long)(unsigned int)hi << 32) | (unsigned int)lo;
}

// ---------------- K1: peak detect (float4) -> per-row x-lists ----------------
// one wave (64 lanes) per row, 4 floats/lane/chunk; 4 rows per block; 1024 blocks
__global__ __launch_bounds__(256) void k_peak(const float* __restrict__ hm,
                                              unsigned short* __restrict__ xlist,
                                              int* __restrict__ rowcount) {
    int row  = blockIdx.x * 4 + (threadIdx.x >> 6);
    int lane = threadIdx.x & 63;
    const float* r = hm + (size_t)row * WW;
    const float4* r4 = (const float4*)r;
    unsigned short* xl = xlist + (size_t)row * ROWCAP;
    int cnt = 0;                         // wave-uniform running count
    for (int ch = 0; ch < 16; ++ch) {
        int v4i = ch * 64 + lane;        // float4 index within the row
        float4 v = r4[v4i];
        float c0 = clampA(v.x), c1 = clampA(v.y), c2 = clampA(v.z), c3 = clampA(v.w);
        bool any4 = (c0 > 0.f) || (c1 > 0.f) || (c2 > 0.f) || (c3 > 0.f);
        unsigned long long bb = __ballot(any4);
        if (bb == 0ull) continue;        // common path: no candidate in 256 pixels
        int pmask = 0;
        if (any4) {
            int x0 = v4i * 4;
            float lft = (x0 > 0)       ? clampA(r[x0 - 1]) : 0.f;
            float rgt = (x0 + 4 < WW)  ? clampA(r[x0 + 4]) : 0.f;
            float cc[4] = {c0, c1, c2, c3};
            float lv[4] = {lft, c0, c1, c2};
            float rv[4] = {c1, c2, c3, rgt};
            #pragma unroll
            for (int e = 0; e < 4; ++e) {
                if (cc[e] > 0.f && cc[e] > lv[e] && cc[e] > rv[e]) {
                    int x = x0 + e;
                    float up = (row > 0)      ? clampA(hm[(size_t)(row - 1) * WW + x]) : 0.f;
                    float dn = (row < HH - 1) ? clampA(hm[(size_t)(row + 1) * WW + x]) : 0.f;
                    if (cc[e] > up && cc[e] > dn) pmask |= (1 << e);
                }
            }
        }
        int pc = __popc(pmask);
        int incl = pc;                   // wave prefix scan (lane order == x order)
        #pragma unroll
        for (int d = 1; d < 64; d <<= 1) {
            int o = __shfl_up(incl, d);
            if (lane >= d) incl += o;
        }
        int pos = cnt + incl - pc;
        while (pmask) {
            int e = __builtin_ctz(pmask);
            if (pos < ROWCAP) xl[pos] = (unsigned short)(v4i * 4 + e);
            ++pos;
            pmask &= pmask - 1;
        }
        cnt += __shfl(incl, 63);         // wave total, uniform
    }
    if (lane == 0) rowcount[row] = min(cnt, ROWCAP);
}

// ---------------- K2: scan row counts + emit coords + inits (single block) -------
__global__ __launch_bounds__(1024) void k_scan(const int* __restrict__ rowcount,
                                               const unsigned short* __restrict__ xlist,
                                               int* __restrict__ Pp,
                                               int* __restrict__ cy, int* __restrict__ cx,
                                               int* __restrict__ rej) {
    __shared__ int sums[1024];
    int tid = threadIdx.x;
    int base = tid * 4;
    int a0 = rowcount[base + 0];
    int a1 = rowcount[base + 1];
    int a2 = rowcount[base + 2];
    int a3 = rowcount[base + 3];
    int s = a0 + a1 + a2 + a3;
    sums[tid] = s;
    __syncthreads();
    for (int d = 1; d < 1024; d <<= 1) {   // Hillis-Steele inclusive scan
        int v = (tid >= d) ? sums[tid - d] : 0;
        __syncthreads();
        if (tid >= d) sums[tid] += v;
        __syncthreads();
    }
    int excl = sums[tid] - s;
    int total = sums[1023];
    int P = min(total, MAXP);
    // emit this thread's 4 rows (row-major global order == jnp.nonzero order)
    int cnts[4] = {a0, a1, a2, a3};
    int pos = excl;
    #pragma unroll
    for (int r = 0; r < 4; ++r) {
        int row = base + r;
        const unsigned short* xl = xlist + (size_t)row * ROWCAP;
        for (int t = 0; t < cnts[r]; ++t) {
            if (pos < MAXP) { cy[pos] = row; cx[pos] = (int)xl[t]; }
            ++pos;
        }
    }
    // fill tail with -1 (jnp.nonzero fill_value)
    for (int i = P + tid; i < MAXP; i += 1024) { cy[i] = -1; cx[i] = -1; }
    // zero reject flags
    for (int i = tid; i < MAXP; i += 1024) rej[i] = 0;
    if (tid == 0) *Pp = P;
}

// ---------------- K3: NMS, j-sliced (replicates XLA f32 arithmetic exactly) ------
__global__ __launch_bounds__(256) void k_nms(const int* __restrict__ cy,
                                             const int* __restrict__ cx,
                                             const int* __restrict__ Pp,
                                             int* __restrict__ rej) {
    int P = *Pp;
    if ((int)(blockIdx.x * 256) >= P) return;             // whole i-block past P
    int jlo = blockIdx.y * 512;
    if (jlo >= P) return;                                 // whole j-slice past P
    int jhi = min(jlo + 512, P);
    __shared__ int   sy[256], sx[256];
    __shared__ float sn2[256];
    int tid = threadIdx.x;
    int i = blockIdx.x * 256 + tid;
    int yi = cy[i], xi = cx[i];
    float n2i = (float)(yi * yi + xi * xi);   // exact int sum, one f32 rounding == XLA
    bool reject = false;
    for (int t0 = jlo; t0 < jhi; t0 += 256) {
        int lim = min(256, jhi - t0);
        if (tid < lim) {
            int yj0 = cy[t0 + tid], xj0 = cx[t0 + tid];
            sy[tid] = yj0; sx[tid] = xj0;
            sn2[tid] = (float)(yj0 * yj0 + xj0 * xj0);
        }
        __syncthreads();
        for (int u = 0; u < lim; ++u) {
            int yj = sy[u], xj = sx[u];
            float dot = (float)(yi * yj + xi * xj);       // products < 2^24: exact
            float d2 = (n2i + sn2[u]) - 2.0f * dot;       // == n2[:,None]+n2[None,:]-2*(cf@cf.T)
            reject = reject || ((d2 > 1.0f) && (d2 < 25.0f));
        }
        __syncthreads();
    }
    if (reject && i < P) atomicOr(&rej[i], 1);            // OR is order-independent
}

// ---------------- K4: batched window gather + label logits + softmax -------------
// block b handles peaks [8b, 8b+8): label_W row loaded once, applied to 8 windows
__global__ __launch_bounds__(256) void k_logits(const float* __restrict__ img,
                                                const float* __restrict__ lW,
                                                const float* __restrict__ lb,
                                                const int* __restrict__ cy,
                                                const int* __restrict__ cx,
                                                const int* __restrict__ rej,
                                                const int* __restrict__ Pp,
                                                float* __restrict__ outP,
                                                float* __restrict__ score,
                                                int* __restrict__ label,
                                                int* __restrict__ validf) {
    int tid = threadIdx.x;
    int i0 = blockIdx.x * 8;
    int P = *Pp;
    bool kp[8];                          // static-indexed only (rule #20)
    int ys[8], xs[8];
    bool anyk = false;
    #pragma unroll
    for (int p = 0; p < 8; ++p) {
        int i = i0 + p;
        kp[p] = (i < P) && (rej[i] == 0);
        anyk |= kp[p];
        ys[p] = cy[i]; xs[p] = cx[i];
    }
    // zero outputs of non-kept rows (recompute flag — no dynamic kp[] index)
    if (tid < 8) {
        int i = i0 + tid;
        bool k2 = (i < P) && (rej[i] == 0);
        if (!k2) {
            #pragma unroll
            for (int o = 0; o < 5; ++o) outP[(size_t)i * 5 + o] = 0.f;
            score[i] = 0.f; label[i] = -1; validf[i] = 0;
        }
    }
    if (!anyk) return;

    float acc[8][5];
    #pragma unroll
    for (int p = 0; p < 8; ++p)
        #pragma unroll
        for (int o = 0; o < 5; ++o) acc[p][o] = 0.f;

    for (int m = 0; m < 12; ++m) {
        int k  = tid + m * 256;          // feature index: c*1024 + wy*32 + wx
        int c  = k >> 10;
        int r  = (k >> 5) & 31;
        int wx = k & 31;
        const float* wr = lW + (size_t)k * 5;
        float w0 = wr[0], w1 = wr[1], w2 = wr[2], w3 = wr[3], w4 = wr[4];
        #pragma unroll
        for (int p = 0; p < 8; ++p) {
            if (!kp[p]) continue;        // uniform across block
            int iy = ys[p] - 16 + r, ix = xs[p] - 16 + wx;
            float f = 0.f;
            if ((unsigned)iy < 4096u && (unsigned)ix < 4096u)
                f = img[(size_t)c * 16777216u + (size_t)iy * 4096u + (unsigned)ix];
            acc[p][0] += f * w0;
            acc[p][1] += f * w1;
            acc[p][2] += f * w2;
            acc[p][3] += f * w3;
            acc[p][4] += f * w4;
        }
    }
    // wave shuffle reduce, then cross-wave via LDS
    __shared__ float wsum[4][8][5];
    int wid = tid >> 6, lane = tid & 63;
    #pragma unroll
    for (int p = 0; p < 8; ++p) {
        #pragma unroll
        for (int off = 32; off > 0; off >>= 1) {
            #pragma unroll
            for (int o = 0; o < 5; ++o) acc[p][o] += __shfl_xor(acc[p][o], off);
        }
        if (lane == 0) {
            #pragma unroll
            for (int o = 0; o < 5; ++o) wsum[wid][p][o] = acc[p][o];
        }
    }
    __syncthreads();
    // per-peak softmax: threads 0..7, one peak each
    if (tid < 8) {
        int i = i0 + tid;
        bool k2 = (i < P) && (rej[i] == 0);
        if (k2) {
            float z[5], sh[5], pr[5];
            #pragma unroll
            for (int o = 0; o < 5; ++o)
                z[o] = wsum[0][tid][o] + wsum[1][tid][o] + wsum[2][tid][o] + wsum[3][tid][o] + lb[o];
            float mx = z[0];
            #pragma unroll
            for (int o = 1; o < 5; ++o) mx = fmaxf(mx, z[o]);
            float s = 0.f;
            #pragma unroll
            for (int o = 0; o < 5; ++o) { sh[o] = z[o] - mx; s += expf(sh[o]); }
            float ls = logf(s);
            float best = -1.f; int bi = 0;
            #pragma unroll
            for (int o = 0; o < 5; ++o) {
                pr[o] = expf(sh[o] - ls);            // exp(log_softmax) as in reference
                if (pr[o] > best) { best = pr[o]; bi = o; }
            }
            int v = (best > 0.3f) ? 1 : 0;
            #pragma unroll
            for (int o = 0; o < 5; ++o) outP[(size_t)i * 5 + o] = v ? pr[o] : 0.f;
            score[i] = best; label[i] = bi; validf[i] = v;
        }
    }
}

// ---------------- K5: per-class top-k (u64 keys) + cue-dir head (single block) ----
__global__ __launch_bounds__(256) void k_topk(const float* __restrict__ score,
                                              const int* __restrict__ label,
                                              const int* __restrict__ validf,
                                              const int* __restrict__ cy,
                                              const int* __restrict__ cx,
                                              const float* __restrict__ img,
                                              const float* __restrict__ dW,
                                              const float* __restrict__ db,
                                              float* __restrict__ out) {
    int tid = threadIdx.x;
    int wid = tid >> 6, lane = tid & 63;
    // cache 32 entries per thread: score bits (0 if invalid) + label
    unsigned int sv[32];
    int labv[32];
    #pragma unroll
    for (int m = 0; m < 32; ++m) {
        int i = m * 256 + tid;
        float s = score[i];
        sv[m]   = validf[i] ? __float_as_uint(s) : 0u;   // valid scores > 0.3 => bits > 0
        labv[m] = label[i];
    }
    __shared__ unsigned long long wbest[4];
    const int KS[5] = {1, 1, 6, 6, 2};
    int outPos = 0;
    int cue0 = 0, cue1 = 0;
    for (int c = 0; c < 5; ++c) {
        unsigned long long prevKey = ~0ull;
        for (int t = 0; t < KS[c]; ++t) {
            // key = (score_bits_if_class_c << 32) | (~i); strictly ordered, distinct.
            // invalid / other-class entries keep (~i) => stable ascending-index picks
            // for the -inf pool, matching jax.lax.top_k.
            unsigned long long best = 0;
            #pragma unroll
            for (int m = 0; m < 32; ++m) {
                int i = m * 256 + tid;
                unsigned int hi = (labv[m] == c) ? sv[m] : 0u;
                unsigned long long key =
                    ((unsigned long long)hi << 32) | (0xFFFFFFFFu - (unsigned int)i);
                if (key >= prevKey) key = 0;   // exclude earlier picks of this class
                if (key > best) best = key;
            }
            #pragma unroll
            for (int off = 32; off > 0; off >>= 1) {
                unsigned long long o = shflx_u64(best, off);
                if (o > best) best = o;
            }
            if (lane == 0) wbest[wid] = best;
            __syncthreads();
            best = wbest[0];
            if (wbest[1] > best) best = wbest[1];
            if (wbest[2] > best) best = wbest[2];
            if (wbest[3] > best) best = wbest[3];
            __syncthreads();   // protect wbest before next round
            prevKey = best;
            int win = (int)(0xFFFFFFFFu - (unsigned int)(best & 0xFFFFFFFFull));
            if (c == 4) { if (t == 0) cue0 = win; else cue1 = win; }
            if (tid == 0) {
                unsigned int hi = (unsigned int)(best >> 32);
                out[40960 + outPos] = hi ? __uint_as_float(hi) : 0.f;  // isfinite ? v : 0
                out[40980 + outPos * 2 + 0] = (float)cy[win];          // sel_peaks
                out[40980 + outPos * 2 + 1] = (float)cx[win];
            }
            ++outPos;
        }
    }
    // ---- cue-dir head: feats[cue_idx] @ dir_W + dir_b, rows flipped ----
    int cueIdx[2] = {cue0, cue1};
    #pragma unroll
    for (int s = 0; s < 2; ++s) {
        int i = (s == 0) ? cueIdx[0] : cueIdx[1];
        int y = max(cy[i], 0), x = max(cx[i], 0);   // starts = clip(coords, 0)
        float a0 = 0.f, a1 = 0.f;
        for (int m = 0; m < 12; ++m) {
            int k  = tid + m * 256;
            int c  = k >> 10;
            int r  = (k >> 5) & 31;
            int wx = k & 31;
            int iy = y - 16 + r, ix = x - 16 + wx;
            float f = 0.f;
            if ((unsigned)iy < 4096u && (unsigned)ix < 4096u)
                f = img[(size_t)c * 16777216u + (size_t)iy * 4096u + (unsigned)ix];
            a0 += f * dW[(size_t)k * 2 + 0];
            a1 += f * dW[(size_t)k * 2 + 1];
        }
        #pragma unroll
        for (int off = 32; off > 0; off >>= 1) {
            a0 += __shfl_xor(a0, off);
            a1 += __shfl_xor(a1, off);
        }
        __shared__ float wa[4][2];
        if (lane == 0) { wa[wid][0] = a0; wa[wid][1] = a1; }
        __syncthreads();
        if (tid == 0) {
            float s0 = wa[0][0] + wa[1][0] + wa[2][0] + wa[3][0] + db[0];
            float s1 = wa[0][1] + wa[1][1] + wa[2][1] + wa[3][1] + db[1];
            // cue_dir = flip(rows): pick s writes output row (1-s)
            out[40976 + (1 - s) * 2 + 0] = s0;
            out[40976 + (1 - s) * 2 + 1] = s1;
        }
        __syncthreads();
    }
}

// ---------------- launch ----------------
extern "C" void kernel_launch(void* const* d_in, const int* in_sizes, int n_in,
                              void* d_out, int out_size, void* d_ws, size_t ws_size,
                              hipStream_t stream) {
    const float* hm  = (const float*)d_in[0];
    const float* img = (const float*)d_in[1];
    const float* lW  = (const float*)d_in[2];
    const float* lb  = (const float*)d_in[3];
    const float* dW  = (const float*)d_in[4];
    const float* db  = (const float*)d_in[5];
    float* out = (float*)d_out;

    uint8_t* w = (uint8_t*)d_ws;
    unsigned short* xlist = (unsigned short*)(w + 0);          // 4096*64*2 = 524288 B
    int*   rowcount = (int*)  (w + 524288);                    // 16384 B
    int*   cy       = (int*)  (w + 540672);                    // 32768 B
    int*   cx       = (int*)  (w + 573440);                    // 32768 B
    int*   rej      = (int*)  (w + 606208);                    // 32768 B
    float* score    = (float*)(w + 638976);                    // 32768 B
    int*   label    = (int*)  (w + 671744);                    // 32768 B
    int*   validf   = (int*)  (w + 704512);                    // 32768 B
    int*   Pp       = (int*)  (w + 737280);                    // 4 B

    hipLaunchKernelGGL(k_peak,   dim3(1024),   dim3(256),  0, stream, hm, xlist, rowcount);
    hipLaunchKernelGGL(k_scan,   dim3(1),      dim3(1024), 0, stream, rowcount, xlist, Pp, cy, cx, rej);
    hipLaunchKernelGGL(k_nms,    dim3(32, 16), dim3(256),  0, stream, cy, cx, Pp, rej);
    hipLaunchKernelGGL(k_logits, dim3(1024),   dim3(256),  0, stream, img, lW, lb, cy, cx, rej, Pp,
                       out, score, label, validf);
    hipLaunchKernelGGL(k_topk,   dim3(1),      dim3(256),  0, stream, score, label, validf, cy, cx,
                       img, dW, db, out);
}